// Round 15
// baseline (385.116 us; speedup 1.0000x reference)
//
#include <hip/hip_runtime.h>

#define N_VNS   8192
#define N_CNS   4096
#define BATCH   1024
#define NUM_ITER 20
#define MAX_E   24576           // == 6 * N_CNS
#define LOG2E   1.44269504088896f
#define LN2     0.693147180559945f
// (2^24-1)/(2^24+1): tanh-domain image of the reference PHI_MAX clip
#define RCLAMP  0x1.fffffcp-1f
// tanh(PHI_MIN/2): tanh-domain image of the reference PHI_MIN clip; also
// keeps rcp(T) finite (never divide by 0)
#define TMIN    4.25e-08f
// LDS word map: T quad-interleaved [0,24576) + scratch 24576; P at PBASE
#define TSCRATCH 24576
#define PBASE    24640
#define PZERO    (PBASE + N_CNS)
#define LDS_WORDS (PZERO + 64)
#define LDS_BYTES (LDS_WORDS * 4)

typedef float v2f __attribute__((ext_vector_type(2)));
typedef float v4f __attribute__((ext_vector_type(4)));

// t (log2-scaled LLR) -> T = tanh(t*ln2/2) = (2^t - 1)/(2^t + 1), signed.
__device__ __forceinline__ float t2T(float t) {
    float tc = fminf(fmaxf(t, -24.0f), 24.0f);
    float E = __builtin_amdgcn_exp2f(tc);
    return (E - 1.0f) * __builtin_amdgcn_rcpf(E + 1.0f);
}

// message value r -> m = log2((1+r)/(1-r)) (= 2atanh(r)*log2e)
__device__ __forceinline__ float r2m(float r) {
    float rc = fminf(fmaxf(r, -RCLAMP), RCLAMP);
    return __builtin_amdgcn_logf((1.0f + rc) * __builtin_amdgcn_rcpf(1.0f - rc));
}

// write guard == BOTH reference clips in tanh domain: TMIN <= |T| <= RCLAMP
__device__ __forceinline__ float guardT(float t) {
    float m = fminf(fmaxf(fabsf(t), TMIN), RCLAMP);
    return __builtin_copysignf(m, t);
}

// slot (16-bit) -> byte addrs of T slot and of its cn's P slot (cheap remat:
// slot<16384 -> cn=slot>>2 ; else cn=(slot>>1)-8192 ; miss -> scratch/zero)
__device__ __forceinline__ void edge_addrs(unsigned sk, unsigned& at, unsigned& ap) {
    bool miss = (sk == 0xFFFFu);
    unsigned cn = (sk < 16384u) ? (sk >> 2) : ((sk >> 1) - 8192u);
    at = miss ? (TSCRATCH * 4u) : (sk * 4u);
    ap = miss ? (PZERO * 4u) : ((PBASE + cn) * 4u);
}

// ---------- setup kernels (run once per launch, ~10 us total) ----------

__global__ void count_edges(const int* __restrict__ vn_con, const int* __restrict__ cn_con,
                            int E, int* __restrict__ vn_cnt, int* __restrict__ cn_cnt) {
    int e = blockIdx.x * 256 + threadIdx.x;
    if (e < E) {
        atomicAdd(&vn_cnt[vn_con[e]], 1);
        atomicAdd(&cn_cnt[cn_con[e]], 1);
    }
}

__global__ void scan_excl(const int* __restrict__ cnt, int n, int* __restrict__ ptr) {
    __shared__ int sh[1024];
    int carry = 0;
    if (threadIdx.x == 0) ptr[0] = 0;
    for (int base = 0; base < n; base += 1024) {
        int i = base + (int)threadIdx.x;
        int v = (i < n) ? cnt[i] : 0;
        sh[threadIdx.x] = v;
        __syncthreads();
        for (int off = 1; off < 1024; off <<= 1) {
            int add = ((int)threadIdx.x >= off) ? sh[threadIdx.x - off] : 0;
            __syncthreads();
            sh[threadIdx.x] += add;
            __syncthreads();
        }
        if (i < n) ptr[i + 1] = carry + sh[threadIdx.x];
        carry += sh[1023];
        __syncthreads();
    }
}

__global__ void fill_vn(const int* __restrict__ vn_con, int E,
                        const int* __restrict__ vn_ptr, int* __restrict__ vn_fill,
                        int* __restrict__ vn_eids) {
    int e = blockIdx.x * 256 + threadIdx.x;
    if (e < E) {
        int v = vn_con[e];
        int slot = atomicAdd(&vn_fill[v], 1);
        vn_eids[vn_ptr[v] + slot] = e;
    }
}

// deterministic CSR: sort each vn's (<=3) edge ids ascending; pack three
// 16-bit T-slots into a uint2 (sentinel 0xFFFF past degree).
// Quad-interleaved T slot: rank<4: cn*4+rank; rank 4,5: 16384 + cn*2 + rank-4
// -> CN phase reads ranks 0-3 as one b128 and ranks 4-5 as one b64.
__global__ void sort_pack_vn(const int* __restrict__ vn_ptr, int* __restrict__ vn_eids,
                             const int* __restrict__ cn_con, const int* __restrict__ cn_ptr,
                             uint2* __restrict__ vn_pack) {
    int v = blockIdx.x * 256 + threadIdx.x;
    if (v >= N_VNS) return;
    int s = vn_ptr[v], n = vn_ptr[v + 1] - s;
    for (int i = 1; i < n; ++i) {
        int key = vn_eids[s + i];
        int j = i - 1;
        while (j >= 0 && vn_eids[s + j] > key) { vn_eids[s + j + 1] = vn_eids[s + j]; --j; }
        vn_eids[s + j + 1] = key;
    }
    unsigned sl[3];
    for (int k = 0; k < 3; ++k) {
        sl[k] = 0xFFFFu;
        if (k < n) {
            int eid = vn_eids[s + k];
            int cn = cn_con[eid];
            unsigned rank = (unsigned)(eid - cn_ptr[cn]);
            sl[k] = (rank < 4) ? ((unsigned)cn * 4 + rank)
                               : (16384u + (unsigned)cn * 2 + (rank - 4));
        }
    }
    vn_pack[v] = make_uint2(sl[0] | (sl[1] << 16), sl[2]);
}

// ---------- the whole decode: one block per batch element ----------
// LDS: T (quad-interleaved): written ONLY by VN (scattered b32), read ONLY by
//        CN (b128+b64, conflict-free). Pad slots stay 1.0 forever.
//      P[N_CNS]: P_c = prod of all 6 T -- written by CN (contiguous b32),
//        read scattered by VN.
// VN recovers excl_e = P * rcp(T_own) from register copy qr, combines in the
// tanh domain (fma-exact), writes guarded T_new. guardT == both ref clips.
// 1024-thread blocks are hard-capped at 64 VGPRs on this toolchain (all
// launch-bounds knobs tried -> 64). Persistent state = 48 regs (pw 16 +
// Tllr 8 + qr 24); the R12/R13 spill came from the scheduler software-
// pipelining the 8-VN unrolled loop (hoisting 24 scattered loads).
// sched_barrier(0) after each VN sub-iteration forbids that hoisting and
// caps live temps ~60 < 64. Latency is covered by TLP (16 waves/CU).

__global__ __launch_bounds__(1024)
void decode(const float* __restrict__ llr_ch, float* __restrict__ out,
            const uint2* __restrict__ vn_pack) {
    extern __shared__ float q[];
    char* qb = (char*)q;

    int b = blockIdx.x, tid = threadIdx.x;
    const float* llr_row = llr_ch + (size_t)b * N_VNS;

    uint2 pw[8];                        // packed 3x16-bit T-slots per VN
    float Tllr[8];                      // guarded tanh(llr_nat/2), loop-invariant
    float qr[8][3];                     // register copy of own T values
    #pragma unroll
    for (int i = 0; i < 8; ++i) {
        int v = i * 1024 + tid;
        pw[i] = vn_pack[v];
        Tllr[i] = guardT(t2T(-llr_row[v] * LOG2E));
    }

    // init: T region (incl. scratch + pads) = 1.0; P zero slot = 0
    #pragma unroll
    for (int k = 0; k < 24; ++k) q[k * 1024 + tid] = 1.0f;
    if (tid == 0) { q[TSCRATCH] = 1.0f; q[PZERO] = 0.0f; }
    __syncthreads();
    // initial T_e = tanh-image of channel LLR (missing edges -> scratch)
    #pragma unroll
    for (int i = 0; i < 8; ++i) {
        float T0 = Tllr[i];
        unsigned s[3] = { pw[i].x & 0xFFFFu, pw[i].x >> 16, pw[i].y & 0xFFFFu };
        #pragma unroll
        for (int k = 0; k < 3; ++k) {
            unsigned at, ap;
            edge_addrs(s[k], at, ap);
            qr[i][k] = T0;
            *(float*)(qb + at) = T0;
        }
        __builtin_amdgcn_sched_barrier(0);
    }
    __syncthreads();

    for (int it = 0; it < NUM_ITER; ++it) {
        // ---- CN phase: P_c = prod of 6 T (b128 + b64 reads, b32 write) ----
        #pragma unroll
        for (int i = 0; i < 4; ++i) {
            unsigned c = (unsigned)(i * 1024 + tid);
            v4f T03 = *(v4f*)(qb + c * 16u);
            v2f T45 = *(v2f*)(qb + 65536u + c * 8u);
            float P = ((((T03.x * T03.y) * T03.z) * T03.w) * T45.x) * T45.y;
            *(float*)(qb + (PBASE * 4u) + c * 4u) = P;
        }
        __syncthreads();
        if (it == NUM_ITER - 1) break;

        // ---- VN phase: excl by division, tanh-domain combine, write T ----
        // sched_barrier(0) per VN: no cross-VN hoisting -> no spill at the
        // immovable 64-VGPR cap.
        #pragma unroll
        for (int i = 0; i < 8; ++i) {
            unsigned s0 = pw[i].x & 0xFFFFu, s1 = pw[i].x >> 16, s2 = pw[i].y & 0xFFFFu;
            unsigned at0, ap0, at1, ap1, at2, ap2;
            edge_addrs(s0, at0, ap0);
            edge_addrs(s1, at1, ap1);
            edge_addrs(s2, at2, ap2);
            float P0 = *(float*)(qb + ap0);
            float P1 = *(float*)(qb + ap1);
            float P2 = *(float*)(qb + ap2);
            float r0 = P0 * __builtin_amdgcn_rcpf(qr[i][0]);
            float r1 = P1 * __builtin_amdgcn_rcpf(qr[i][1]);
            float r2 = P2 * __builtin_amdgcn_rcpf(qr[i][2]);
            float T = Tllr[i];
            float A12 = __builtin_fmaf(r1, r2, 1.0f), B12 = r1 + r2;
            float A02 = __builtin_fmaf(r0, r2, 1.0f), B02 = r0 + r2;
            float A01 = __builtin_fmaf(r0, r1, 1.0f), B01 = r0 + r1;
            float n0 = __builtin_fmaf(T, A12, B12), d0 = __builtin_fmaf(T, B12, A12);
            float n1 = __builtin_fmaf(T, A02, B02), d1 = __builtin_fmaf(T, B02, A02);
            float n2 = __builtin_fmaf(T, A01, B01), d2 = __builtin_fmaf(T, B01, A01);
            float t0 = guardT(n0 * __builtin_amdgcn_rcpf(d0));
            float t1 = guardT(n1 * __builtin_amdgcn_rcpf(d1));
            float t2 = guardT(n2 * __builtin_amdgcn_rcpf(d2));
            qr[i][0] = t0; *(float*)(qb + at0) = t0;
            qr[i][1] = t1; *(float*)(qb + at1) = t1;
            qr[i][2] = t2; *(float*)(qb + at2) = t2;
            __builtin_amdgcn_sched_barrier(0);
        }
        __syncthreads();
    }

    // ---- marginalization: out[b][v] = -(llr + sum_e m_e) * ln2 ----
    float* orow = out + (size_t)b * N_VNS;
    #pragma unroll
    for (int i = 0; i < 8; ++i) {
        int v = i * 1024 + tid;
        unsigned s0 = pw[i].x & 0xFFFFu, s1 = pw[i].x >> 16, s2 = pw[i].y & 0xFFFFu;
        unsigned at0, ap0, at1, ap1, at2, ap2;
        edge_addrs(s0, at0, ap0);
        edge_addrs(s1, at1, ap1);
        edge_addrs(s2, at2, ap2);
        float ns = -llr_row[v] * LOG2E;     // re-read channel llr (L3-hot)
        ns += r2m(*(float*)(qb + ap0) * __builtin_amdgcn_rcpf(qr[i][0]));
        ns += r2m(*(float*)(qb + ap1) * __builtin_amdgcn_rcpf(qr[i][1]));
        ns += r2m(*(float*)(qb + ap2) * __builtin_amdgcn_rcpf(qr[i][2]));
        orow[v] = -ns * LN2;
        __builtin_amdgcn_sched_barrier(0);
    }
}

extern "C" void kernel_launch(void* const* d_in, const int* in_sizes, int n_in,
                              void* d_out, int out_size, void* d_ws, size_t ws_size,
                              hipStream_t stream) {
    const float* llr_ch = (const float*)d_in[0];
    const int* vn_con = (const int*)d_in[1];
    const int* cn_con = (const int*)d_in[2];
    int E = in_sizes[1];
    float* out = (float*)d_out;

    char* ws = (char*)d_ws;
    size_t off = 0;
    auto alloc = [&](size_t bytes) -> void* {
        void* ptr = ws + off;
        off = (off + bytes + 255) & ~(size_t)255;
        return ptr;
    };
    int* vn_ptr  = (int*)alloc((N_VNS + 1) * 4);
    int* cn_ptr  = (int*)alloc((N_CNS + 1) * 4);
    int* vn_cnt  = (int*)alloc(N_VNS * 4);
    int* cn_cnt  = (int*)alloc(N_CNS * 4);
    int* vn_fill = (int*)alloc(N_VNS * 4);
    int* vn_eids = (int*)alloc((size_t)E * 4);
    uint2* vn_pack = (uint2*)alloc((size_t)N_VNS * 8);

    hipMemsetAsync(vn_cnt, 0, N_VNS * 4, stream);
    hipMemsetAsync(cn_cnt, 0, N_CNS * 4, stream);
    hipMemsetAsync(vn_fill, 0, N_VNS * 4, stream);

    count_edges<<<(E + 255) / 256, 256, 0, stream>>>(vn_con, cn_con, E, vn_cnt, cn_cnt);
    scan_excl<<<1, 1024, 0, stream>>>(vn_cnt, N_VNS, vn_ptr);
    scan_excl<<<1, 1024, 0, stream>>>(cn_cnt, N_CNS, cn_ptr);
    fill_vn<<<(E + 255) / 256, 256, 0, stream>>>(vn_con, E, vn_ptr, vn_fill, vn_eids);
    sort_pack_vn<<<(N_VNS + 255) / 256, 256, 0, stream>>>(vn_ptr, vn_eids, cn_con, cn_ptr,
                                                          vn_pack);

    static bool attr_set = false;
    if (!attr_set) {
        hipFuncSetAttribute((const void*)decode,
                            hipFuncAttributeMaxDynamicSharedMemorySize, LDS_BYTES);
        attr_set = true;
    }
    decode<<<BATCH, 1024, LDS_BYTES, stream>>>(llr_ch, out, vn_pack);
}

// Round 17
// 343.779 us; speedup vs baseline: 1.1202x; 1.1202x over previous
//
#include <hip/hip_runtime.h>

#define N_VNS   8192
#define N_CNS   4096
#define BATCH   1024
#define NUM_ITER 20
#define MAX_E   24576           // == 6 * N_CNS, rank-pair-interleaved layout
#define LOG2E   1.44269504088896f
#define LN2     0.693147180559945f
// (2^24-1)/(2^24+1): tanh-domain image of BOTH reference clips
#define RCLAMP  0x1.fffffcp-1f
#define ZSLOT   24576           // always-zero slot (tanh-add identity), written ONCE
#define ZBYTE   (ZSLOT * 4)
#define MAXPADS 2048
#define LDS_BYTES ((MAX_E + 64) * 4)

typedef float v2f __attribute__((ext_vector_type(2)));

// t (log2-scaled LLR) -> T = tanh(t*ln2/2) = (2^t - 1)/(2^t + 1), signed.
__device__ __forceinline__ float t2T(float t) {
    float tc = fminf(fmaxf(t, -24.0f), 24.0f);
    float E = __builtin_amdgcn_exp2f(tc);
    float T = (E - 1.0f) * __builtin_amdgcn_rcpf(E + 1.0f);
    return fminf(fmaxf(T, -RCLAMP), RCLAMP);
}

// exclusion product r -> message m = log2((1+r)/(1-r)) (= 2atanh(r)*log2e)
__device__ __forceinline__ float r2m(float r) {
    float rc = fminf(fmaxf(r, -RCLAMP), RCLAMP);
    return __builtin_amdgcn_logf((1.0f + rc) * __builtin_amdgcn_rcpf(1.0f - rc));
}

// pair-interleaved slot: ranks (2j, 2j+1) of cn adjacent -> CN phase uses b64
__device__ __forceinline__ unsigned qslot(unsigned rank, unsigned cn) {
    return (rank >> 1) * (2 * N_CNS) + cn * 2 + (rank & 1);
}

// ---------- setup kernels (run once per launch, ~10 us total) ----------

__global__ void count_edges(const int* __restrict__ vn_con, const int* __restrict__ cn_con,
                            int E, int* __restrict__ vn_cnt, int* __restrict__ cn_cnt) {
    int e = blockIdx.x * 256 + threadIdx.x;
    if (e < E) {
        atomicAdd(&vn_cnt[vn_con[e]], 1);
        atomicAdd(&cn_cnt[cn_con[e]], 1);
    }
}

__global__ void scan_excl(const int* __restrict__ cnt, int n, int* __restrict__ ptr) {
    __shared__ int sh[1024];
    int carry = 0;
    if (threadIdx.x == 0) ptr[0] = 0;
    for (int base = 0; base < n; base += 1024) {
        int i = base + (int)threadIdx.x;
        int v = (i < n) ? cnt[i] : 0;
        sh[threadIdx.x] = v;
        __syncthreads();
        for (int off = 1; off < 1024; off <<= 1) {
            int add = ((int)threadIdx.x >= off) ? sh[threadIdx.x - off] : 0;
            __syncthreads();
            sh[threadIdx.x] += add;
            __syncthreads();
        }
        if (i < n) ptr[i + 1] = carry + sh[threadIdx.x];
        carry += sh[1023];
        __syncthreads();
    }
}

__global__ void fill_vn(const int* __restrict__ vn_con, int E,
                        const int* __restrict__ vn_ptr, int* __restrict__ vn_fill,
                        int* __restrict__ vn_eids) {
    int e = blockIdx.x * 256 + threadIdx.x;
    if (e < E) {
        int v = vn_con[e];
        int slot = atomicAdd(&vn_fill[v], 1);
        vn_eids[vn_ptr[v] + slot] = e;
    }
}

// deterministic CSR: sort each vn's (<=3) edge ids ascending; pack three
// 16-bit pair-interleaved slots into a uint2 (sentinel 0xFFFF past degree).
__global__ void sort_pack_vn(const int* __restrict__ vn_ptr, int* __restrict__ vn_eids,
                             const int* __restrict__ cn_con, const int* __restrict__ cn_ptr,
                             uint2* __restrict__ vn_pack) {
    int v = blockIdx.x * 256 + threadIdx.x;
    if (v >= N_VNS) return;
    int s = vn_ptr[v], n = vn_ptr[v + 1] - s;
    for (int i = 1; i < n; ++i) {
        int key = vn_eids[s + i];
        int j = i - 1;
        while (j >= 0 && vn_eids[s + j] > key) { vn_eids[s + j + 1] = vn_eids[s + j]; --j; }
        vn_eids[s + j + 1] = key;
    }
    unsigned sl[3];
    for (int k = 0; k < 3; ++k) {
        sl[k] = 0xFFFFu;
        if (k < n) {
            int eid = vn_eids[s + k];
            int cn = cn_con[eid];
            unsigned rank = (unsigned)(eid - cn_ptr[cn]);
            sl[k] = qslot(rank, (unsigned)cn);
        }
    }
    vn_pack[v] = make_uint2(sl[0] | (sl[1] << 16), sl[2] | 0xFFFF0000u);
}

// DETERMINISTIC pad list (no atomics): pads before cn c = 6*c - cn_ptr[c]
// (closed form), so every launch/replay produces the identical pad_slots
// array. pad_slots pre-memset to 0xFF (0xFFFF sentinel). Thread tid of the
// decode block restores pad_slots[tid] and pad_slots[1024+tid].
__global__ void pad_fill(const int* __restrict__ cn_ptr,
                         unsigned short* __restrict__ pad_slots) {
    int c = blockIdx.x * 256 + threadIdx.x;
    if (c >= N_CNS) return;
    int s = cn_ptr[c];
    int deg = cn_ptr[c + 1] - s;
    int base = 6 * c - s;               // total pads among cns < c
    for (int r = deg; r < 6; ++r) {
        int idx = base + (r - deg);
        if (idx < MAXPADS)
            pad_slots[idx] = (unsigned short)qslot((unsigned)r, (unsigned)c);
    }
}

// ---------- the whole decode: one block per batch element ----------
// LDS q (pair-interleaved [3][N_CNS][2]) holds, alternately:
//   after VN phase: T_e = tanh(t_e_nat/2), clamped +/-RCLAMP (pads = 1.0)
//   after CN phase: excl_e = prod_{k in cn(e), k!=e} T_k  (signed)
// ZSLOT: written 0 ONCE at init, never stored to again (missing-edge writes
// are skip-stores) -> reads always 0, zero write races anywhere.
// CN phase: 3x ds_read_b64, 12 muls (prefix/suffix), 3x ds_write_b64 per CN.
// VN phase: branchless reads (|q| <= RCLAMP by construction, clamps dead),
// fma-exact tanh combine, 3 rcp, predicated scattered writes.
// Fully deterministic across calls/replays: pad list closed-form, no benign
// same-address races, all ws state recomputed per launch.

__global__ __launch_bounds__(1024)
void decode(const float* __restrict__ llr_ch, float* __restrict__ out,
            const uint2* __restrict__ vn_pack,
            const unsigned short* __restrict__ pad_slots) {
    extern __shared__ float q[];
    char* qb = (char*)q;

    int b = blockIdx.x, tid = threadIdx.x;
    const float* llr_row = llr_ch + (size_t)b * N_VNS;

    float llr[8];                       // log2-scaled channel LLR
    float Tllr[8];                      // tanh(llr_nat/2), loop-invariant
    unsigned a[8][3];                   // byte addresses of own edge slots
    unsigned pad0, pad1;
    {
        unsigned p0 = pad_slots[tid];
        unsigned p1 = pad_slots[1024 + tid];
        pad0 = (p0 == 0xFFFFu) ? 0xFFFFFFFFu : p0 * 4u;
        pad1 = (p1 == 0xFFFFu) ? 0xFFFFFFFFu : p1 * 4u;
        #pragma unroll
        for (int i = 0; i < 8; ++i) {
            int v = i * 1024 + tid;
            uint2 pw = vn_pack[v];
            llr[i] = -llr_row[v] * LOG2E;
            Tllr[i] = t2T(llr[i]);
            unsigned s0 = pw.x & 0xFFFFu, s1 = pw.x >> 16, s2 = pw.y & 0xFFFFu;
            a[i][0] = (s0 == 0xFFFFu) ? ZBYTE : s0 * 4;
            a[i][1] = (s1 == 0xFFFFu) ? ZBYTE : s1 * 4;
            a[i][2] = (s2 == 0xFFFFu) ? ZBYTE : s2 * 4;
        }
    }

    // init: all slots 1.0 (covers pads), Z slot 0 (only write to it ever)
    #pragma unroll
    for (int k = 0; k < 24; ++k) q[k * 1024 + tid] = 1.0f;
    if (tid == 0) q[ZSLOT] = 0.0f;
    __syncthreads();
    #pragma unroll
    for (int i = 0; i < 8; ++i) {
        float T0 = Tllr[i];
        #pragma unroll
        for (int k = 0; k < 3; ++k)
            if (a[i][k] != ZBYTE) *(float*)(qb + a[i][k]) = T0;
    }
    __syncthreads();

    for (int it = 0; it < NUM_ITER; ++it) {
        // ---- CN phase: per-edge exclusion products via prefix/suffix ----
        #pragma unroll
        for (int i = 0; i < 4; ++i) {
            unsigned c8 = (unsigned)(i * 1024 + tid) * 8u;
            v2f T01 = *(v2f*)(qb + c8);
            v2f T23 = *(v2f*)(qb + 32768 + c8);
            v2f T45 = *(v2f*)(qb + 65536 + c8);
            float T0 = T01.x, T1 = T01.y, T2 = T23.x, T3 = T23.y, T4 = T45.x, T5 = T45.y;
            float p1 = T0 * T1, p2 = p1 * T2, p3 = p2 * T3, p4 = p3 * T4;
            float s4 = T5 * T4, s3 = s4 * T3, s2 = s3 * T2, s1 = s2 * T1;
            v2f e01 = { s1, T0 * s2 };
            v2f e23 = { p1 * s3, p2 * s4 };
            v2f e45 = { p3 * T5, p4 };
            *(v2f*)(qb + c8) = e01;
            *(v2f*)(qb + 32768 + c8) = e23;
            *(v2f*)(qb + 65536 + c8) = e45;
        }
        __syncthreads();
        if (it == NUM_ITER - 1) break;

        // ---- VN phase: tanh-domain combine; predicated scattered writes ----
        #pragma unroll
        for (int i = 0; i < 8; ++i) {
            float r0 = *(float*)(qb + a[i][0]);   // ZBYTE reads 0 (identity)
            float r1 = *(float*)(qb + a[i][1]);
            float r2 = *(float*)(qb + a[i][2]);
            float T = Tllr[i];
            float A12 = __builtin_fmaf(r1, r2, 1.0f), B12 = r1 + r2;
            float A02 = __builtin_fmaf(r0, r2, 1.0f), B02 = r0 + r2;
            float A01 = __builtin_fmaf(r0, r1, 1.0f), B01 = r0 + r1;
            float n0 = __builtin_fmaf(T, A12, B12), d0 = __builtin_fmaf(T, B12, A12);
            float n1 = __builtin_fmaf(T, A02, B02), d1 = __builtin_fmaf(T, B02, A02);
            float n2 = __builtin_fmaf(T, A01, B01), d2 = __builtin_fmaf(T, B01, A01);
            float t0 = n0 * __builtin_amdgcn_rcpf(d0);
            float t1 = n1 * __builtin_amdgcn_rcpf(d1);
            float t2 = n2 * __builtin_amdgcn_rcpf(d2);
            t0 = fminf(fmaxf(t0, -RCLAMP), RCLAMP);
            t1 = fminf(fmaxf(t1, -RCLAMP), RCLAMP);
            t2 = fminf(fmaxf(t2, -RCLAMP), RCLAMP);
            if (a[i][0] != ZBYTE) *(float*)(qb + a[i][0]) = t0;
            if (a[i][1] != ZBYTE) *(float*)(qb + a[i][1]) = t1;
            if (a[i][2] != ZBYTE) *(float*)(qb + a[i][2]) = t2;
        }
        if (pad0 != 0xFFFFFFFFu) *(float*)(qb + pad0) = 1.0f;
        if (pad1 != 0xFFFFFFFFu) *(float*)(qb + pad1) = 1.0f;
        __syncthreads();
    }

    // ---- marginalization: out[b][v] = -(llr + sum_e m_e) * ln2 ----
    float* orow = out + (size_t)b * N_VNS;
    #pragma unroll
    for (int i = 0; i < 8; ++i) {
        float ns = llr[i];
        ns += r2m(*(float*)(qb + a[i][0]));   // r2m(0) = 0 for missing edges
        ns += r2m(*(float*)(qb + a[i][1]));
        ns += r2m(*(float*)(qb + a[i][2]));
        orow[i * 1024 + tid] = -ns * LN2;
    }
}

extern "C" void kernel_launch(void* const* d_in, const int* in_sizes, int n_in,
                              void* d_out, int out_size, void* d_ws, size_t ws_size,
                              hipStream_t stream) {
    const float* llr_ch = (const float*)d_in[0];
    const int* vn_con = (const int*)d_in[1];
    const int* cn_con = (const int*)d_in[2];
    int E = in_sizes[1];
    float* out = (float*)d_out;

    char* ws = (char*)d_ws;
    size_t off = 0;
    auto alloc = [&](size_t bytes) -> void* {
        void* ptr = ws + off;
        off = (off + bytes + 255) & ~(size_t)255;
        return ptr;
    };
    int* vn_ptr  = (int*)alloc((N_VNS + 1) * 4);
    int* cn_ptr  = (int*)alloc((N_CNS + 1) * 4);
    int* vn_cnt  = (int*)alloc(N_VNS * 4);
    int* cn_cnt  = (int*)alloc(N_CNS * 4);
    int* vn_fill = (int*)alloc(N_VNS * 4);
    int* vn_eids = (int*)alloc((size_t)E * 4);
    uint2* vn_pack = (uint2*)alloc((size_t)N_VNS * 8);
    unsigned short* pad_slots = (unsigned short*)alloc(MAXPADS * 2);

    hipMemsetAsync(vn_cnt, 0, N_VNS * 4, stream);
    hipMemsetAsync(cn_cnt, 0, N_CNS * 4, stream);
    hipMemsetAsync(vn_fill, 0, N_VNS * 4, stream);
    hipMemsetAsync(pad_slots, 0xFF, MAXPADS * 2, stream);

    count_edges<<<(E + 255) / 256, 256, 0, stream>>>(vn_con, cn_con, E, vn_cnt, cn_cnt);
    scan_excl<<<1, 1024, 0, stream>>>(vn_cnt, N_VNS, vn_ptr);
    scan_excl<<<1, 1024, 0, stream>>>(cn_cnt, N_CNS, cn_ptr);
    fill_vn<<<(E + 255) / 256, 256, 0, stream>>>(vn_con, E, vn_ptr, vn_fill, vn_eids);
    sort_pack_vn<<<(N_VNS + 255) / 256, 256, 0, stream>>>(vn_ptr, vn_eids, cn_con, cn_ptr,
                                                          vn_pack);
    pad_fill<<<(N_CNS + 255) / 256, 256, 0, stream>>>(cn_ptr, pad_slots);

    static bool attr_set = false;
    if (!attr_set) {
        hipFuncSetAttribute((const void*)decode,
                            hipFuncAttributeMaxDynamicSharedMemorySize, LDS_BYTES);
        attr_set = true;
    }
    decode<<<BATCH, 1024, LDS_BYTES, stream>>>(llr_ch, out, vn_pack, pad_slots);
}